// Round 1
// baseline (8560.296 us; speedup 1.0000x reference)
//
#include <hip/hip_runtime.h>
#include <math.h>

#define NB 32
#define NT 16
#define NH 768
#define NV 32000

// Reduced-region geometry (only rows feeding memory[:, :196, :] are computed):
// conv1 out: [32][64][34][112]   (rows 0..33 of 112)
// pool  out: [32][64][17][56]    (rows 0..16 of 56)
// conv2 out: [32][128][16][56]   (rows 0..15 of 56)
// conv3 out: [32][256][8][28]    (rows 0..7 of 28)
// conv4 out -> memory [32][196][768]  (rows 0..6 of 28)

__device__ __forceinline__ float sigmoidf_(float x) { return 1.f / (1.f + expf(-x)); }

// ---------------- BN scale/bias precompute ----------------
__global__ void bn_prep(const float* __restrict__ g, const float* __restrict__ b,
                        const float* __restrict__ m, const float* __restrict__ v,
                        float* __restrict__ scale, float* __restrict__ bias, int C) {
    int i = blockIdx.x * 256 + threadIdx.x;
    if (i < C) {
        float inv = g[i] * rsqrtf(v[i] + 1e-5f);
        scale[i] = inv;
        bias[i] = b[i] - m[i] * inv;
    }
}

// ---------------- conv1: 7x7 s2 p3 + BN + ReLU ----------------
// grid (34, 64, 32), block 128 (x = output col, 112 active)
__global__ __launch_bounds__(128) void conv1_kernel(
    const float* __restrict__ img, const float* __restrict__ w,
    const float* __restrict__ scale, const float* __restrict__ bias,
    float* __restrict__ out) {
    int x = threadIdx.x;
    if (x >= 112) return;
    int y = blockIdx.x;      // 0..33
    int co = blockIdx.y;     // 0..63
    int b = blockIdx.z;      // 0..31
    float acc = 0.f;
    for (int ci = 0; ci < 3; ++ci) {
        const float* ip = img + ((size_t)(b * 3 + ci)) * 224 * 224;
        const float* wp = w + co * 147 + ci * 49;
        #pragma unroll
        for (int ky = 0; ky < 7; ++ky) {
            int iy = 2 * y - 3 + ky;
            if ((unsigned)iy < 224u) {
                const float* row = ip + iy * 224;
                #pragma unroll
                for (int kx = 0; kx < 7; ++kx) {
                    int ix = 2 * x - 3 + kx;
                    float val = ((unsigned)ix < 224u) ? row[ix] : 0.f;
                    acc = fmaf(val, wp[ky * 7 + kx], acc);
                }
            }
        }
    }
    float r = fmaxf(acc * scale[co] + bias[co], 0.f);
    out[(((size_t)(b * 64 + co)) * 34 + y) * 112 + x] = r;
}

// ---------------- maxpool 3x3 s2 p1 ----------------
__global__ __launch_bounds__(256) void pool_kernel(const float* __restrict__ in, float* __restrict__ out) {
    int idx = blockIdx.x * 256 + threadIdx.x;
    const int total = 32 * 64 * 17 * 56;
    if (idx >= total) return;
    int x = idx % 56;
    int y = (idx / 56) % 17;
    int c = (idx / (56 * 17)) % 64;
    int b = idx / (56 * 17 * 64);
    const float* p = in + ((size_t)(b * 64 + c)) * 34 * 112;
    float m = -INFINITY;
    #pragma unroll
    for (int ky = -1; ky <= 1; ++ky) {
        int iy = 2 * y + ky;
        if ((unsigned)iy < 34u) {
            #pragma unroll
            for (int kx = -1; kx <= 1; ++kx) {
                int ix = 2 * x + kx;
                if ((unsigned)ix < 112u) m = fmaxf(m, p[iy * 112 + ix]);
            }
        }
    }
    out[idx] = m;
}

// ---------------- generic 3x3 conv + BN + ReLU ----------------
template <int CIN, int HIN, int WIN, int HOUT, int WOUT, int STRIDE, int MEMOUT>
__global__ __launch_bounds__(256) void conv3x3_kernel(
    const float* __restrict__ in, const float* __restrict__ w,
    const float* __restrict__ scale, const float* __restrict__ bias,
    float* __restrict__ out, int COUT) {
    int idx = blockIdx.x * 256 + threadIdx.x;
    int total = 32 * COUT * HOUT * WOUT;
    if (idx >= total) return;
    int x = idx % WOUT;
    int y = (idx / WOUT) % HOUT;
    int co = (idx / (WOUT * HOUT)) % COUT;
    int b = idx / (WOUT * HOUT * COUT);
    int iy0 = STRIDE * y - 1;
    int ix0 = STRIDE * x - 1;
    float acc = 0.f;
    const float* wbase = w + (size_t)co * CIN * 9;
    const float* ibase = in + (size_t)b * CIN * HIN * WIN;
    for (int ci = 0; ci < CIN; ++ci) {
        const float* ip = ibase + (size_t)ci * HIN * WIN;
        const float* wp = wbase + ci * 9;
        #pragma unroll
        for (int ky = 0; ky < 3; ++ky) {
            int iy = iy0 + ky;
            if ((unsigned)iy < (unsigned)HIN) {
                const float* row = ip + iy * WIN;
                #pragma unroll
                for (int kx = 0; kx < 3; ++kx) {
                    int ix = ix0 + kx;
                    float val = ((unsigned)ix < (unsigned)WIN) ? row[ix] : 0.f;
                    acc = fmaf(val, wp[ky * 3 + kx], acc);
                }
            }
        }
    }
    float r = fmaxf(acc * scale[co] + bias[co], 0.f);
    if (MEMOUT) {
        // memory layout [b][m][768], m = y*WOUT + x  (WOUT=28, HOUT=7 -> m<196)
        out[((size_t)b * (HOUT * WOUT) + y * WOUT + x) * (size_t)COUT + co] = r;
    } else {
        out[idx] = r;
    }
}

// ---------------- embedding gather: e512[r][k], r = t*32+b ----------------
__global__ __launch_bounds__(256) void gather_emb(const int* __restrict__ caps,
                                                  const float* __restrict__ table,
                                                  float* __restrict__ e512) {
    int idx = blockIdx.x * 256 + threadIdx.x;  // 512*768
    int k = idx % NH;
    int r = idx / NH;
    int t = r >> 5;
    int b = r & 31;
    e512[idx] = table[(size_t)caps[b * NT + t] * NH + k];
}

// ---------------- tiled f32 GEMM: C[m][n] = sum_k A[m][k]*B[n][k] + bias ----------------
// block 256, tile 64x64, BK=16. M = gridDim.y*64 (exact), N = gridDim.x*64 (exact), K % 16 == 0.
template <int REMAP>
__global__ __launch_bounds__(256) void gemm_abt(
    const float* __restrict__ A, const float* __restrict__ B,
    const float* __restrict__ bias1, const float* __restrict__ bias2,
    float* __restrict__ C, int lda, int ldb, int N, int K) {
    __shared__ float As[16][68];
    __shared__ float Bs[16][68];
    int tid = threadIdx.x;
    int n0 = blockIdx.x * 64, m0 = blockIdx.y * 64;
    int lk = tid & 15, lr = tid >> 4;
    int ty = tid >> 4, tx = tid & 15;
    float acc[4][4] = {};
    for (int k0 = 0; k0 < K; k0 += 16) {
        #pragma unroll
        for (int it = 0; it < 4; ++it) {
            As[lk][lr + 16 * it] = A[(size_t)(m0 + lr + 16 * it) * lda + k0 + lk];
            Bs[lk][lr + 16 * it] = B[(size_t)(n0 + lr + 16 * it) * ldb + k0 + lk];
        }
        __syncthreads();
        #pragma unroll
        for (int kk = 0; kk < 16; ++kk) {
            float4 a = *(const float4*)&As[kk][ty * 4];
            float4 bv = *(const float4*)&Bs[kk][tx * 4];
            acc[0][0] = fmaf(a.x, bv.x, acc[0][0]);
            acc[0][1] = fmaf(a.x, bv.y, acc[0][1]);
            acc[0][2] = fmaf(a.x, bv.z, acc[0][2]);
            acc[0][3] = fmaf(a.x, bv.w, acc[0][3]);
            acc[1][0] = fmaf(a.y, bv.x, acc[1][0]);
            acc[1][1] = fmaf(a.y, bv.y, acc[1][1]);
            acc[1][2] = fmaf(a.y, bv.z, acc[1][2]);
            acc[1][3] = fmaf(a.y, bv.w, acc[1][3]);
            acc[2][0] = fmaf(a.z, bv.x, acc[2][0]);
            acc[2][1] = fmaf(a.z, bv.y, acc[2][1]);
            acc[2][2] = fmaf(a.z, bv.z, acc[2][2]);
            acc[2][3] = fmaf(a.z, bv.w, acc[2][3]);
            acc[3][0] = fmaf(a.w, bv.x, acc[3][0]);
            acc[3][1] = fmaf(a.w, bv.y, acc[3][1]);
            acc[3][2] = fmaf(a.w, bv.z, acc[3][2]);
            acc[3][3] = fmaf(a.w, bv.w, acc[3][3]);
        }
        __syncthreads();
    }
    #pragma unroll
    for (int i = 0; i < 4; ++i) {
        int m = m0 + ty * 4 + i;
        #pragma unroll
        for (int j = 0; j < 4; ++j) {
            int n = n0 + tx * 4 + j;
            float v = acc[i][j];
            if (bias1) v += bias1[n];
            if (bias2) v += bias2[n];
            if (REMAP) {  // A row r = t*32+b -> logits[(b*16+t)*NV + n]
                int t = m >> 5, b = m & 31;
                C[(size_t)((b << 4) + t) * NV + n] = v;
            } else {
                C[(size_t)m * N + n] = v;
            }
        }
    }
}

// ---------------- attention step: q = h@Wt, scores, softmax, ctx ----------------
// grid 32 (batch), block 768
__global__ __launch_bounds__(768) void attn_step(
    const float* __restrict__ h, const float* __restrict__ attn_w,
    const float* __restrict__ mem, float* __restrict__ ctx) {
    __shared__ float q[NH];
    __shared__ float p[196];
    __shared__ float red[16];
    int b = blockIdx.x, tid = threadIdx.x;
    const float4* h4 = (const float4*)(h + (size_t)b * NH);
    {
        const float4* w4 = (const float4*)(attn_w + (size_t)tid * NH);
        float acc = 0.f;
        #pragma unroll 4
        for (int k = 0; k < NH / 4; ++k) {
            float4 a = h4[k], w = w4[k];
            acc += a.x * w.x + a.y * w.y + a.z * w.z + a.w * w.w;
        }
        q[tid] = acc;
    }
    __syncthreads();
    float sc = -INFINITY;
    if (tid < 196) {
        const float4* m4 = (const float4*)(mem + ((size_t)b * 196 + tid) * NH);
        const float4* q4 = (const float4*)q;
        float acc = 0.f;
        #pragma unroll 4
        for (int k = 0; k < NH / 4; ++k) {
            float4 a = q4[k], w = m4[k];
            acc += a.x * w.x + a.y * w.y + a.z * w.z + a.w * w.w;
        }
        sc = acc;
    }
    // block max
    float v = sc;
    #pragma unroll
    for (int off = 32; off; off >>= 1) v = fmaxf(v, __shfl_down(v, off));
    if ((tid & 63) == 0) red[tid >> 6] = v;
    __syncthreads();
    if (tid == 0) {
        float m = red[0];
        for (int i = 1; i < 12; ++i) m = fmaxf(m, red[i]);
        red[12] = m;
    }
    __syncthreads();
    float mx = red[12];
    float e = (tid < 196) ? expf(sc - mx) : 0.f;
    __syncthreads();
    // block sum
    v = e;
    #pragma unroll
    for (int off = 32; off; off >>= 1) v += __shfl_down(v, off);
    if ((tid & 63) == 0) red[tid >> 6] = v;
    __syncthreads();
    if (tid == 0) {
        float s = red[0];
        for (int i = 1; i < 12; ++i) s += red[i];
        red[12] = 1.f / s;
    }
    __syncthreads();
    if (tid < 196) p[tid] = e * red[12];
    __syncthreads();
    {
        float acc = 0.f;
        const float* mbase = mem + (size_t)b * 196 * NH + tid;
        #pragma unroll 4
        for (int m = 0; m < 196; ++m) acc = fmaf(p[m], mbase[(size_t)m * NH], acc);
        ctx[(size_t)b * NH + tid] = acc;
    }
}

// ---------------- gate matvecs: gates = eg_t + ctx@w_ih[:,768:].T + h@w_hh.T ----------------
// grid (12, 32), block 256 -> thread per (b, j)
__global__ __launch_bounds__(256) void step_gates(
    const float* __restrict__ ctx, const float* __restrict__ h,
    const float* __restrict__ w_ih, const float* __restrict__ w_hh,
    const float* __restrict__ eg_t, float* __restrict__ gates) {
    int j = blockIdx.x * 256 + threadIdx.x;  // 0..3071
    int b = blockIdx.y;
    const float4* c4 = (const float4*)(ctx + (size_t)b * NH);
    const float4* h4 = (const float4*)(h + (size_t)b * NH);
    const float4* wi = (const float4*)(w_ih + (size_t)j * (2 * NH) + NH);
    const float4* wh = (const float4*)(w_hh + (size_t)j * NH);
    float acc = eg_t[(size_t)b * 3072 + j];
    float acc2 = 0.f;
    #pragma unroll 4
    for (int k = 0; k < NH / 4; ++k) {
        float4 a = c4[k], w = wi[k];
        acc += a.x * w.x + a.y * w.y + a.z * w.z + a.w * w.w;
        float4 a2 = h4[k], w2 = wh[k];
        acc2 += a2.x * w2.x + a2.y * w2.y + a2.z * w2.z + a2.w * w2.w;
    }
    gates[(size_t)b * 3072 + j] = acc + acc2;
}

// ---------------- LSTM cell pointwise ----------------
__global__ __launch_bounds__(256) void step_cell(
    const float* __restrict__ gates, float* __restrict__ h, float* __restrict__ c,
    float* __restrict__ hall_t) {
    int idx = blockIdx.x * 256 + threadIdx.x;
    if (idx >= NB * NH) return;
    int b = idx / NH;
    int k = idx % NH;
    const float* g = gates + (size_t)b * 3072;
    float gi = g[k], gf = g[NH + k], gg = g[2 * NH + k], go = g[3 * NH + k];
    float cn = sigmoidf_(gf) * c[idx] + sigmoidf_(gi) * tanhf(gg);
    float hn = sigmoidf_(go) * tanhf(cn);
    c[idx] = cn;
    h[idx] = hn;
    hall_t[idx] = hn;
}

__global__ __launch_bounds__(256) void zero_hc(float* __restrict__ h, float* __restrict__ c) {
    int i = blockIdx.x * 256 + threadIdx.x;
    if (i < NB * NH) { h[i] = 0.f; c[i] = 0.f; }
}

__global__ __launch_bounds__(256) void copy_hc(const float* __restrict__ h, const float* __restrict__ c,
                                               float* __restrict__ out) {
    int i = blockIdx.x * 256 + threadIdx.x;
    if (i < NB * NH) {
        out[(size_t)NB * NT * NV + i] = h[i];
        out[(size_t)NB * NT * NV + NB * NH + i] = c[i];
    }
}

extern "C" void kernel_launch(void* const* d_in, const int* in_sizes, int n_in,
                              void* d_out, int out_size, void* d_ws, size_t ws_size,
                              hipStream_t stream) {
    const float* images   = (const float*)d_in[0];
    const int*   captions = (const int*)d_in[1];
    const float* conv1_w  = (const float*)d_in[2];
    const float* bn1_g = (const float*)d_in[3], *bn1_b = (const float*)d_in[4];
    const float* bn1_m = (const float*)d_in[5], *bn1_v = (const float*)d_in[6];
    const float* conv2_w  = (const float*)d_in[7];
    const float* bn2_g = (const float*)d_in[8], *bn2_b = (const float*)d_in[9];
    const float* bn2_m = (const float*)d_in[10], *bn2_v = (const float*)d_in[11];
    const float* conv3_w  = (const float*)d_in[12];
    const float* bn3_g = (const float*)d_in[13], *bn3_b = (const float*)d_in[14];
    const float* bn3_m = (const float*)d_in[15], *bn3_v = (const float*)d_in[16];
    const float* conv4_w  = (const float*)d_in[17];
    const float* bn4_g = (const float*)d_in[18], *bn4_b = (const float*)d_in[19];
    const float* bn4_m = (const float*)d_in[20], *bn4_v = (const float*)d_in[21];
    const float* emb_table = (const float*)d_in[22];
    const float* attn_w   = (const float*)d_in[23];
    const float* w_ih     = (const float*)d_in[24];
    const float* w_hh     = (const float*)d_in[25];
    const float* b_ih     = (const float*)d_in[26];
    const float* b_hh     = (const float*)d_in[27];
    const float* fc_w     = (const float*)d_in[28];
    const float* fc_b     = (const float*)d_in[29];
    float* out = (float*)d_out;

    // ---- workspace layout (floats) ----
    float* ws = (float*)d_ws;
    size_t off = 0;
    auto alloc = [&](size_t n) { float* p = ws + off; off += (n + 63) & ~(size_t)63; return p; };
    float* s1 = alloc(64);  float* bb1 = alloc(64);
    float* s2 = alloc(128); float* bb2 = alloc(128);
    float* s3 = alloc(256); float* bb3 = alloc(256);
    float* s4 = alloc(768); float* bb4 = alloc(768);
    float* x1   = alloc(32 * 64 * 34 * 112);   // conv1 out; reused for conv2 out
    float* xp   = alloc(32 * 64 * 17 * 56);    // pool out; reused for conv3 out
    float* memv = alloc((size_t)32 * 196 * 768);
    float* e512 = alloc(512 * 768);
    float* eg   = alloc((size_t)512 * 3072);
    float* Hall = alloc(512 * 768);
    float* hbuf = alloc(NB * NH);
    float* cbuf = alloc(NB * NH);
    float* ctx  = alloc(NB * NH);
    float* gates = alloc(NB * 3072);
    float* x2 = x1;  // conv2 out (x1 dead after pool)
    float* x3 = xp;  // conv3 out (xp dead after conv2)

    // ---- BN params ----
    bn_prep<<<1, 256, 0, stream>>>(bn1_g, bn1_b, bn1_m, bn1_v, s1, bb1, 64);
    bn_prep<<<1, 256, 0, stream>>>(bn2_g, bn2_b, bn2_m, bn2_v, s2, bb2, 128);
    bn_prep<<<1, 256, 0, stream>>>(bn3_g, bn3_b, bn3_m, bn3_v, s3, bb3, 256);
    bn_prep<<<3, 256, 0, stream>>>(bn4_g, bn4_b, bn4_m, bn4_v, s4, bb4, 768);

    // ---- encoder (reduced region) ----
    conv1_kernel<<<dim3(34, 64, 32), 128, 0, stream>>>(images, conv1_w, s1, bb1, x1);
    pool_kernel<<<(32 * 64 * 17 * 56 + 255) / 256, 256, 0, stream>>>(x1, xp);
    conv3x3_kernel<64, 17, 56, 16, 56, 1, 0>
        <<<(32 * 128 * 16 * 56 + 255) / 256, 256, 0, stream>>>(xp, conv2_w, s2, bb2, x2, 128);
    conv3x3_kernel<128, 16, 56, 8, 28, 2, 0>
        <<<(32 * 256 * 8 * 28 + 255) / 256, 256, 0, stream>>>(x2, conv3_w, s3, bb3, x3, 256);
    conv3x3_kernel<256, 8, 28, 7, 28, 1, 1>
        <<<(32 * 768 * 7 * 28 + 255) / 256, 256, 0, stream>>>(x3, conv4_w, s4, bb4, memv, 768);

    // ---- decoder precompute ----
    gather_emb<<<(512 * 768) / 256, 256, 0, stream>>>(captions, emb_table, e512);
    // eg[r][j] = e512[r] . w_ih[j][0:768] + b_ih[j] + b_hh[j]
    gemm_abt<0><<<dim3(3072 / 64, 512 / 64), 256, 0, stream>>>(
        e512, w_ih, b_ih, b_hh, eg, NH, 2 * NH, 3072, NH);
    zero_hc<<<(NB * NH + 255) / 256, 256, 0, stream>>>(hbuf, cbuf);

    // ---- sequential decoder ----
    for (int t = 0; t < NT; ++t) {
        attn_step<<<NB, NH, 0, stream>>>(hbuf, attn_w, memv, ctx);
        step_gates<<<dim3(3072 / 256, NB), 256, 0, stream>>>(
            ctx, hbuf, w_ih, w_hh, eg + (size_t)t * NB * 3072, gates);
        step_cell<<<(NB * NH + 255) / 256, 256, 0, stream>>>(
            gates, hbuf, cbuf, Hall + (size_t)t * NB * NH);
    }

    // ---- vocab projection for all 16 steps at once ----
    gemm_abt<1><<<dim3(NV / 64, 512 / 64), 256, 0, stream>>>(
        Hall, fc_w, fc_b, nullptr, out, NH, NH, NV, NH);

    copy_hc<<<(NB * NH + 255) / 256, 256, 0, stream>>>(hbuf, cbuf, out);
}